// Round 6
// baseline (430.418 us; speedup 1.0000x reference)
//
#include <hip/hip_runtime.h>

// LIF recurrence: X [B,T,N] f32 -> spikes [B,T,N] f32. B=32, T=64, N=32768.
// Independent per (b,n); sequential over t. Stream-bound: 537 MB app traffic
// (HBM-side ~394 MB: L3 absorbs ~half the X reads; FETCH=132MB WRITE=262MB).
//
// R8: R5's full-T burst (xs[64], ~139us) fixed store-gating but cost
// occupancy (VGPR~84 -> 6 waves/SIMD) and made read pressure BURSTY: a wave
// spends ~2K cycles in compute+store (IEEE /5.0f is a ~10-instr sequence)
// exerting zero read demand, so only ~40% of waves feed HBM at any instant
// (2 TB/s read-side, nothing saturated). R0-R4 A/B showed occupancy is the
// strongest lever (float2@32waves beat float4@16 by 1.5x).
//
// Fix: ping-pong half-bursts. xs0=loads t0..15, xs1=t16..31 issued up
// front (loads before any store); each consume block refills its own regs
// with the block 32 steps ahead. Live xs = 32 regs -> VGPR ~48-56,
// launch_bounds(256,8) -> 8 waves/SIMD = 32 waves/CU; AND every wave keeps
// 16-32 loads outstanding until its last block = continuous read pressure.
// Store-gating stays defeated: consumed loads are always older than the
// interleaved stores by >= 1 full block (~1500cy), so in-order vmcnt waits
// never block on store retirement in steady state.
// Strict fp preserved (contract off, true /5.0f divide): absmax must stay 0.

constexpr int B = 32;
constexpr int T = 64;
constexpr int N = 32768;
constexpr int NTHREADS = B * N;      // 1,048,576 threads = 16384 waves

__global__ __launch_bounds__(256, 8) void lif_kernel(const float* __restrict__ X,
                                                     float* __restrict__ out) {
    // Match numpy's separately-rounded mul/add (no FMA contraction): fusing
    // changes rounding and can flip threshold decisions.
#pragma clang fp contract(off)
    const int i = blockIdx.x * blockDim.x + threadIdx.x;  // [0, B*N)
    const int b = i >> 15;               // i / N   (N = 32768)
    const int n = i & (N - 1);           // i % N
    const int base = b * (T * N) + n;    // <= 67.1M floats -> fits int

    const float* __restrict__ Xp = X + base;
    float* __restrict__ Op = out + base;

    float mem = 0.f, ca = 0.f;

    // Named fixed-size arrays, fully unrolled -> registers (rule #20).
    float xs0[16], xs1[16];

    // Phase 1: 32 loads issued before anything else (loads-first ordering).
#pragma unroll
    for (int j = 0; j < 16; ++j) xs0[j] = Xp[j * N];
#pragma unroll
    for (int j = 0; j < 16; ++j) xs1[j] = Xp[(16 + j) * N];
    __builtin_amdgcn_sched_barrier(0);

#define LIFSTEP(xv, t)                                        \
    {                                                         \
        float m_ = mem / 5.0f + (1.0f + 0.1f * ca) * (xv);    \
        float s_ = ((m_ - 0.5f) > 0.0f) ? 1.0f : 0.0f;        \
        mem = (1.0f - s_) * m_;                               \
        ca = 0.5f * ca + (1.0f - s_);                         \
        Op[(t) * N] = s_;                                     \
    }

    // Block 0: consume t=0..15 from xs0, refill xs0 with t=32..47.
#pragma unroll
    for (int j = 0; j < 16; ++j) {
        const float xv = xs0[j];
        xs0[j] = Xp[(32 + j) * N];
        LIFSTEP(xv, j)
    }
    __builtin_amdgcn_sched_barrier(0);

    // Block 1: consume t=16..31 from xs1, refill xs1 with t=48..63.
#pragma unroll
    for (int j = 0; j < 16; ++j) {
        const float xv = xs1[j];
        xs1[j] = Xp[(48 + j) * N];
        LIFSTEP(xv, 16 + j)
    }
    __builtin_amdgcn_sched_barrier(0);

    // Block 2: consume t=32..47 (no refill).
#pragma unroll
    for (int j = 0; j < 16; ++j) {
        LIFSTEP(xs0[j], 32 + j)
    }
    __builtin_amdgcn_sched_barrier(0);

    // Block 3: consume t=48..63.
#pragma unroll
    for (int j = 0; j < 16; ++j) {
        LIFSTEP(xs1[j], 48 + j)
    }
#undef LIFSTEP
}

extern "C" void kernel_launch(void* const* d_in, const int* in_sizes, int n_in,
                              void* d_out, int out_size, void* d_ws, size_t ws_size,
                              hipStream_t stream) {
    const float* X = (const float*)d_in[0];
    float* out = (float*)d_out;
    const int block = 256;
    const int grid = NTHREADS / block;  // 4096 blocks
    lif_kernel<<<grid, block, 0, stream>>>(X, out);
}